// Round 9
// baseline (545.461 us; speedup 1.0000x reference)
//
#include <hip/hip_runtime.h>
#include <stdint.h>

#define LOG2F 0.693147180559945f

typedef __attribute__((ext_vector_type(8))) short short8;
typedef __attribute__((ext_vector_type(4))) float f32x4;

// shifted softplus: softplus(x) - log(2), stable form
__device__ __forceinline__ float ssp(float x){
  float t = __expf(-fabsf(x));
  return fmaxf(x, 0.0f) + __logf(1.0f + t) - LOG2F;
}

// fp32 -> bf16 round-to-nearest-even (16-bit pattern in low bits)
__device__ __forceinline__ uint32_t bf16rn(float x){
  uint32_t u = __float_as_uint(x);
  return (u + 0x7fffu + ((u >> 16) & 1u)) >> 16;
}
// split x ~= hi + lo (both bf16). hi RNE, lo = RNE(x - hi): ~16 mantissa bits kept.
__device__ __forceinline__ void split2(float x, unsigned short &h, unsigned short &l){
  uint32_t hb = bf16rn(x);
  h = (unsigned short)hb;
  float hf = __uint_as_float(hb << 16);
  l = (unsigned short)bf16rn(x - hf);
}

// ============================================================================
// MFMA fragment packing (mfma_f32_16x16x32_bf16) — HW-validated in round 2:
//   A-frag: lane l, elem i <- A[l&15][(l>>4)*8 + i]
//   B-frag: lane l, elem i <- B[(l>>4)*8 + i][l&15]
//   C/D   : lane l, reg  r -> C[(l>>4)*4 + r][l&15]
// Split-bf16 GEMM: D += Ah*Bh + Ah*Bl + Al*Bh  (3 MFMAs, fp32 accumulate)
// Frag LDS layout (32-row tiles): granule = hl*512 + q*32 + (row^q), q=col>>3.
// ============================================================================

// ---------- xs precompute + zero vacc + zero cnt (fused) ----------
__global__ __launch_bounds__(256) void k_xconv(
    const float* __restrict__ x, unsigned short* __restrict__ xs,
    float* __restrict__ vacc, int* __restrict__ cnt, int total)
{
  int i = (blockIdx.x * 256 + threadIdx.x) * 4;
  if (i >= total) return;
  int row = i >> 7, col = i & 127;
  float4 f4 = *(const float4*)(x + i);
  ushort4 h4, l4;
  split2(ssp(f4.x), h4.x, l4.x);
  split2(ssp(f4.y), h4.y, l4.y);
  split2(ssp(f4.z), h4.z, l4.z);
  split2(ssp(f4.w), h4.w, l4.w);
  *(ushort4*)(xs + (size_t)row * 256 + col)       = h4;
  *(ushort4*)(xs + (size_t)row * 256 + 128 + col) = l4;
  *(float4*)(vacc + i) = (float4){0.f, 0.f, 0.f, 0.f};
  if (col == 0) cnt[row] = 0;
}

// ---------- W pre-conversion + edge histogram (fused; cnt zeroed by k_xconv) ----------
__global__ __launch_bounds__(256) void k_wconv(
    const float* __restrict__ Wj, const float* __restrict__ Wg,
    const float* __restrict__ Wi, const float* __restrict__ Wf,
    const float* __restrict__ Wint, const float* __restrict__ Watm,
    const float* __restrict__ Wout,
    unsigned short* __restrict__ ws, int ni, int na, int no,
    const int* __restrict__ idx_i, int* __restrict__ cnt, int E)
{
  const int nmat = 3 + ni + na + no;
  int t = blockIdx.x * 256 + threadIdx.x;
  int m = t >> 11, r = t & 2047;
  if (m < nmat){
    const float* src;
    if      (m == 0)           src = Wj;
    else if (m == 1)           src = Wi;
    else if (m <= 1 + ni)      src = Wint + (size_t)(m - 2) * 16384;
    else if (m == 2 + ni)      src = Wf;
    else if (m <= 2 + ni + na) src = Watm + (size_t)(m - 3 - ni) * 16384;
    else                       src = Wout + (size_t)(m - 3 - ni - na) * 16384;
    int lane = r & 63, s = (r >> 6) & 3, ct = r >> 8;
    int col = ct * 16 + (lane & 15);
    int k0  = s * 32 + (lane >> 4) * 8;
    union { unsigned short u[8]; uint4 v; } H, L;
#pragma unroll
    for (int i = 0; i < 8; ++i) split2(src[(size_t)(k0 + i) * 128 + col], H.u[i], L.u[i]);
    ((uint4*)ws)[(size_t)m * 4096 + ((ct * 4 + s) * 2 + 0) * 64 + lane] = H.v;
    ((uint4*)ws)[(size_t)m * 4096 + ((ct * 4 + s) * 2 + 1) * 64 + lane] = L.v;
  } else {
    int uu = t - nmat * 2048;
    if (uu < 512){
      int lane = uu & 63, ct = uu >> 6;
      int col = ct * 16 + (lane & 15);
      int k0  = (lane >> 4) * 8;
      union { unsigned short u8[8]; uint4 v; } H, L;
#pragma unroll
      for (int i = 0; i < 8; ++i) split2(Wg[(size_t)(k0 + i) * 128 + col], H.u8[i], L.u8[i]);
      ((uint4*)ws)[(size_t)nmat * 4096 + (ct * 2 + 0) * 64 + lane] = H.v;
      ((uint4*)ws)[(size_t)nmat * 4096 + (ct * 2 + 1) * 64 + lane] = L.v;
    }
  }
  const int stride = gridDim.x * 256;
  for (int e = blockIdx.x * 256 + threadIdx.x; e < E; e += stride)
    atomicAdd(&cnt[idx_i[e]], 1);
}

// ---------- counting sort: block scan, then scatter with folded bsums-prefix ----------
__global__ __launch_bounds__(256) void k_scan1(
    int* __restrict__ cnt, int* __restrict__ bsums, int N)
{
  __shared__ int sh[256];
  const int t = threadIdx.x;
  const int base = blockIdx.x * 2048 + t * 8;
  int loc[8], s = 0;
#pragma unroll
  for (int k = 0; k < 8; ++k){
    int v = (base + k < N) ? cnt[base + k] : 0;
    loc[k] = s; s += v;
  }
  sh[t] = s;
  __syncthreads();
  const int own = s;
  for (int off = 1; off < 256; off <<= 1){
    int v = (t >= off) ? sh[t - off] : 0;
    __syncthreads();
    sh[t] += v;
    __syncthreads();
  }
  const int ex = sh[t] - own;
#pragma unroll
  for (int k = 0; k < 8; ++k)
    if (base + k < N) cnt[base + k] = ex + loc[k];
  if (t == 255) bsums[blockIdx.x] = sh[255];
}

// fallback only (nblk > 64)
__global__ void k_scan2(int* __restrict__ bsums, int nblk){
  if (threadIdx.x == 0 && blockIdx.x == 0){
    int run = 0;
    for (int b = 0; b < nblk; ++b){ int v = bsums[b]; bsums[b] = run; run += v; }
  }
}

// scatter; if pref_in_kernel, computes the exclusive prefix of bsums (nblk<=64)
// redundantly per block via a 64-lane shfl scan (bsums is L2-hot).
__global__ __launch_bounds__(256) void k_scatter(
    const int* __restrict__ idx_i, int* __restrict__ cnt,
    const int* __restrict__ bsums, int* __restrict__ perm, int E,
    int nblk, int pref_in_kernel)
{
  __shared__ int spref[64];
  const int t = threadIdx.x;
  if (pref_in_kernel){
    if (t < 64){
      int v = (t < nblk) ? bsums[t] : 0;
      int x = v;
#pragma unroll
      for (int off = 1; off < 64; off <<= 1){
        int y = __shfl_up(x, off);
        if (t >= off) x += y;
      }
      spref[t] = x - v;   // exclusive prefix
    }
  } else {
    if (t < 64) spref[t] = (t < nblk) ? bsums[t] : 0;  // bsums already prefixed
  }
  __syncthreads();
  int e = blockIdx.x * 256 + t;
  if (e < E){
    int ii = idx_i[e];
    int p = atomicAdd(&cnt[ii], 1) + spref[ii >> 11];
    perm[p] = e;
  }
}

// ---------- edge kernel v3: 4-tile software pipeline (reg-staged xs gather) ----------
// Block = 128 edges (4 tiles x 32). Prologue loads all perm/idx for the 4 tiles;
// xs rows double-buffered in registers: tile tt+1's gather issues right after
// tile tt's LDS write, hiding ~900cy random-gather latency under barrier+MFMA+
// epilogue. vp_s is a separate LDS buffer (no ahl alias) -> 3 barriers/tile.
__global__ __launch_bounds__(256, 4) void k_edge(
    const unsigned short* __restrict__ xs, const float* __restrict__ g,
    const int* __restrict__ idx_i, const int* __restrict__ idx_j,
    const int* __restrict__ perm,
    const short8* __restrict__ wjf, const short8* __restrict__ wgf,
    const float* __restrict__ bj, float* vacc, int E)
{
  __shared__ short8 ahl[1024];     // 16 KB
  __shared__ short8 ghl[256];      //  4 KB
  __shared__ float  vp_s[128*33];  // 16.9 KB (separate: no alias with ahl)
  __shared__ int    ii_s[32];

  const int t    = threadIdx.x;
  const int lane = t & 63;
  const int w    = t >> 6;
  const int l15  = lane & 15;
  const int lq   = lane >> 4;
  const int ebase = blockIdx.x * 128;

  const int rowA = t >> 3;
  const int q0   = (t & 7) * 2;

  // hoisted epilogue constants
  const int colA = (w*2 + 0)*16 + l15;
  const int colB = (w*2 + 1)*16 + l15;
  const float bjA = bj[colA], bjB = bj[colB];

  // --- prologue: indices for all 4 tiles (role-split) ---
  int jA[4] = {0,0,0,0}, egi[4] = {0,0,0,0}, iiv[4] = {-1,-1,-1,-1};
#pragma unroll
  for (int tt = 0; tt < 4; ++tt){
    int pe = ebase + tt*32 + rowA;
    int e = (pe < E) ? perm[pe] : 0;
    jA[tt] = idx_j[e];
  }
  if (t < 64){
    const int rowG = t >> 1;
#pragma unroll
    for (int tt = 0; tt < 4; ++tt){
      int pe = ebase + tt*32 + rowG;
      egi[tt] = (pe < E) ? perm[pe] : 0;
    }
  } else if (t < 96){
    const int rr = t - 64;
#pragma unroll
    for (int tt = 0; tt < 4; ++tt){
      int pe = ebase + tt*32 + rr;
      iiv[tt] = (pe < E) ? idx_i[perm[pe]] : -1;
    }
  }

  // --- A staging double buffer; preload tile 0 ---
  short8 A0a, A0b, A0c, A0d, A1a, A1b, A1c, A1d;
  {
    const short8* xp = (const short8*)(xs + (size_t)jA[0] * 256);
    A0a = xp[q0]; A0b = xp[q0+1]; A0c = xp[16+q0]; A0d = xp[16+q0+1];
  }

#pragma unroll
  for (int tt = 0; tt < 4; ++tt){
    // write current A buffer -> LDS
    {
      short8 ca, cb, cc, cd;
      if ((tt & 1) == 0){ ca=A0a; cb=A0b; cc=A0c; cd=A0d; }
      else              { ca=A1a; cb=A1b; cc=A1c; cd=A1d; }
      ahl[0*512 + (q0+0)*32 + (rowA ^ (q0+0))] = ca;
      ahl[0*512 + (q0+1)*32 + (rowA ^ (q0+1))] = cb;
      ahl[1*512 + (q0+0)*32 + (rowA ^ (q0+0))] = cc;
      ahl[1*512 + (q0+1)*32 + (rowA ^ (q0+1))] = cd;
    }
    // prefetch next tile's A rows (latency hides under barrier+MFMA+epilogue)
    if (tt < 3){
      const short8* xp = (const short8*)(xs + (size_t)jA[tt+1] * 256);
      if ((tt & 1) == 0){ A1a=xp[q0]; A1b=xp[q0+1]; A1c=xp[16+q0]; A1d=xp[16+q0+1]; }
      else              { A0a=xp[q0]; A0b=xp[q0+1]; A0c=xp[16+q0]; A0d=xp[16+q0+1]; }
    }
    // g staging (coalesced, L2-friendly) + ii
    if (t < 64){
      const int rowG = t >> 1, qg0 = (t & 1) * 2;
      const float4* gp = (const float4*)(g + (size_t)egi[tt] * 32 + (t & 1) * 16);
      float4 f0 = gp[0], f1 = gp[1], f2 = gp[2], f3 = gp[3];
      float vv[16] = {f0.x,f0.y,f0.z,f0.w, f1.x,f1.y,f1.z,f1.w,
                      f2.x,f2.y,f2.z,f2.w, f3.x,f3.y,f3.z,f3.w};
      short8 fh0, fh1, fl0, fl1;
#pragma unroll
      for (int i2 = 0; i2 < 8; ++i2){
        unsigned short hh, ll; split2(vv[i2], hh, ll);
        fh0[i2] = (short)hh; fl0[i2] = (short)ll;
      }
#pragma unroll
      for (int i2 = 0; i2 < 8; ++i2){
        unsigned short hh, ll; split2(vv[8+i2], hh, ll);
        fh1[i2] = (short)hh; fl1[i2] = (short)ll;
      }
      ghl[0*128 + (qg0+0)*32 + (rowG ^ (qg0+0))] = fh0;
      ghl[0*128 + (qg0+1)*32 + (rowG ^ (qg0+1))] = fh1;
      ghl[1*128 + (qg0+0)*32 + (rowG ^ (qg0+0))] = fl0;
      ghl[1*128 + (qg0+1)*32 + (rowG ^ (qg0+1))] = fl1;
    } else if (t < 96){
      ii_s[t - 64] = iiv[tt];
    }
    __syncthreads();   // b1: LDS staging visible

    // --- MFMA: message (K=128) and gate (K=32), split-bf16 3x ---
    f32x4 am[2][2], ag[2][2];
#pragma unroll
    for (int a = 0; a < 2; ++a)
#pragma unroll
      for (int b = 0; b < 2; ++b){
        am[a][b] = (f32x4){0.f, 0.f, 0.f, 0.f};
        ag[a][b] = (f32x4){0.f, 0.f, 0.f, 0.f};
      }

#pragma unroll
    for (int s = 0; s < 4; ++s){
      const int q = s * 4 + lq;
      short8 a0h = ahl[0*512 + q*32 + ((l15     ) ^ q)];
      short8 a0l = ahl[1*512 + q*32 + ((l15     ) ^ q)];
      short8 a1h = ahl[0*512 + q*32 + ((16 + l15) ^ q)];
      short8 a1l = ahl[1*512 + q*32 + ((16 + l15) ^ q)];
#pragma unroll
      for (int c = 0; c < 2; ++c){
        const int ct = w * 2 + c;
        short8 bh = wjf[((ct*4 + s)*2 + 0)*64 + lane];
        short8 bl = wjf[((ct*4 + s)*2 + 1)*64 + lane];
        am[0][c] = __builtin_amdgcn_mfma_f32_16x16x32_bf16(a0h, bh, am[0][c], 0, 0, 0);
        am[0][c] = __builtin_amdgcn_mfma_f32_16x16x32_bf16(a0h, bl, am[0][c], 0, 0, 0);
        am[0][c] = __builtin_amdgcn_mfma_f32_16x16x32_bf16(a0l, bh, am[0][c], 0, 0, 0);
        am[1][c] = __builtin_amdgcn_mfma_f32_16x16x32_bf16(a1h, bh, am[1][c], 0, 0, 0);
        am[1][c] = __builtin_amdgcn_mfma_f32_16x16x32_bf16(a1h, bl, am[1][c], 0, 0, 0);
        am[1][c] = __builtin_amdgcn_mfma_f32_16x16x32_bf16(a1l, bh, am[1][c], 0, 0, 0);
      }
    }
    {
      const int q = lq;
      short8 g0h = ghl[0*128 + q*32 + ((l15     ) ^ q)];
      short8 g0l = ghl[1*128 + q*32 + ((l15     ) ^ q)];
      short8 g1h = ghl[0*128 + q*32 + ((16 + l15) ^ q)];
      short8 g1l = ghl[1*128 + q*32 + ((16 + l15) ^ q)];
#pragma unroll
      for (int c = 0; c < 2; ++c){
        const int ct = w * 2 + c;
        short8 bh = wgf[(ct*2 + 0)*64 + lane];
        short8 bl = wgf[(ct*2 + 1)*64 + lane];
        ag[0][c] = __builtin_amdgcn_mfma_f32_16x16x32_bf16(g0h, bh, ag[0][c], 0, 0, 0);
        ag[0][c] = __builtin_amdgcn_mfma_f32_16x16x32_bf16(g0h, bl, ag[0][c], 0, 0, 0);
        ag[0][c] = __builtin_amdgcn_mfma_f32_16x16x32_bf16(g0l, bh, ag[0][c], 0, 0, 0);
        ag[1][c] = __builtin_amdgcn_mfma_f32_16x16x32_bf16(g1h, bh, ag[1][c], 0, 0, 0);
        ag[1][c] = __builtin_amdgcn_mfma_f32_16x16x32_bf16(g1h, bl, ag[1][c], 0, 0, 0);
        ag[1][c] = __builtin_amdgcn_mfma_f32_16x16x32_bf16(g1l, bh, ag[1][c], 0, 0, 0);
      }
    }

    // --- epilogue: vp -> transposed LDS, parallel segmented flush ---
#pragma unroll
    for (int c = 0; c < 2; ++c){
      const int col = (c == 0) ? colA : colB;
      const float bjv = (c == 0) ? bjA : bjB;
#pragma unroll
      for (int rt = 0; rt < 2; ++rt)
#pragma unroll
        for (int r = 0; r < 4; ++r){
          const int row = rt * 16 + lq * 4 + r;
          vp_s[col * 33 + row] = ssp(am[rt][c][r] + bjv) * ag[rt][c][r];
        }
    }
    __syncthreads();   // b2: vp_s visible
    {
      const int col = t & 127;
      const int rbase = (t >> 7) * 16;
      float acc = 0.f;
      int curi = -1;
#pragma unroll
      for (int r = 0; r < 16; ++r){
        const int ii = ii_s[rbase + r];
        const float v = vp_s[col * 33 + rbase + r];
        if (ii == curi) acc += v;
        else {
          if (curi >= 0) atomicAdd(&vacc[(size_t)curi * 128 + col], acc);
          acc = v; curi = ii;
        }
      }
      if (curi >= 0) atomicAdd(&vacc[(size_t)curi * 128 + col], acc);
    }
    __syncthreads();   // b3: flush reads done before next tile's staging clobbers
  }
}

// ---------- fused atom-side chain, v2 (round-6 known-good, unchanged) ----------
// NOTE: vacc aliases out[0:N*128]; each block reads only rows it owns before
// writing o to them at kernel end. xs (if aliased to h-half) is dead by now.
__global__ __launch_bounds__(256) void k_chain(
    const float* __restrict__ x, const float* vacc,
    const short8* __restrict__ wcf,
    const float* __restrict__ bi, const float* __restrict__ bf_,
    const float* __restrict__ u,
    const float* __restrict__ bint, const float* __restrict__ batm,
    const float* __restrict__ bout,
    float* out, int N, int ni, int na, int no)
{
  __shared__ short8 ahl[2][1024];   // 2 x 16 KB frag buffers

  const int t    = threadIdx.x;
  const int lane = t & 63;
  const int w    = t >> 6;
  const int l15  = lane & 15;
  const int lq   = lane >> 4;
  const int r0   = blockIdx.x * 32;

  const int col0 = (w*2 + 0)*16 + l15;
  const int col1 = (w*2 + 1)*16 + l15;
  const int q0c = col0 >> 3, e0c = col0 & 7;
  const int q1c = col1 >> 3, e1c = col1 & 7;

  f32x4 am[2][2];
  int cur = 0;

  auto frag_put = [&](int b, int row, int qc, int ec, float v){
    unsigned short hh, ll;
    split2(v, hh, ll);
    unsigned short* base = (unsigned short*)&ahl[b][0];
    const int idx = (qc*32 + (row ^ qc))*8 + ec;
    base[idx]        = hh;
    base[4096 + idx] = ll;
  };

  auto gemm = [&](const short8* __restrict__ wf){
    const short8* A = &ahl[cur][0];
#pragma unroll
    for (int a = 0; a < 2; ++a)
#pragma unroll
      for (int b = 0; b < 2; ++b) am[a][b] = (f32x4){0.f, 0.f, 0.f, 0.f};
#pragma unroll
    for (int s = 0; s < 4; ++s){
      const int q = s * 4 + lq;
      short8 a0h = A[0*512 + q*32 + ((l15     ) ^ q)];
      short8 a0l = A[1*512 + q*32 + ((l15     ) ^ q)];
      short8 a1h = A[0*512 + q*32 + ((16 + l15) ^ q)];
      short8 a1l = A[1*512 + q*32 + ((16 + l15) ^ q)];
#pragma unroll
      for (int c = 0; c < 2; ++c){
        const int ct = w * 2 + c;
        short8 bh = wf[((ct*4 + s)*2 + 0)*64 + lane];
        short8 bl = wf[((ct*4 + s)*2 + 1)*64 + lane];
        am[0][c] = __builtin_amdgcn_mfma_f32_16x16x32_bf16(a0h, bh, am[0][c], 0, 0, 0);
        am[0][c] = __builtin_amdgcn_mfma_f32_16x16x32_bf16(a0h, bl, am[0][c], 0, 0, 0);
        am[0][c] = __builtin_amdgcn_mfma_f32_16x16x32_bf16(a0l, bh, am[0][c], 0, 0, 0);
        am[1][c] = __builtin_amdgcn_mfma_f32_16x16x32_bf16(a1h, bh, am[1][c], 0, 0, 0);
        am[1][c] = __builtin_amdgcn_mfma_f32_16x16x32_bf16(a1h, bl, am[1][c], 0, 0, 0);
        am[1][c] = __builtin_amdgcn_mfma_f32_16x16x32_bf16(a1l, bh, am[1][c], 0, 0, 0);
      }
    }
  };

  auto put_ssp_state = [&](float (&st)[2][2][4]){
    const int b = cur ^ 1;
#pragma unroll
    for (int rt = 0; rt < 2; ++rt)
#pragma unroll
      for (int r = 0; r < 4; ++r){
        const int row = rt*16 + lq*4 + r;
        frag_put(b, row, q0c, e0c, ssp(st[rt][0][r]));
        frag_put(b, row, q1c, e1c, ssp(st[rt][1][r]));
      }
    __syncthreads();
    cur = b;
  };
  auto put_ssp_amb = [&](float b0, float b1){
    const int b = cur ^ 1;
#pragma unroll
    for (int rt = 0; rt < 2; ++rt)
#pragma unroll
      for (int r = 0; r < 4; ++r){
        const int row = rt*16 + lq*4 + r;
        frag_put(b, row, q0c, e0c, ssp(am[rt][0][r] + b0));
        frag_put(b, row, q1c, e1c, ssp(am[rt][1][r] + b1));
      }
    __syncthreads();
    cur = b;
  };

  auto residual = [&](float (&st)[2][2][4], const short8* wf, const float* bvec){
    const float b0 = bvec[col0], b1 = bvec[col1];
    put_ssp_state(st);
    gemm(wf);
    put_ssp_amb(b0, b1);
    gemm(wf);
#pragma unroll
    for (int rt = 0; rt < 2; ++rt)
#pragma unroll
      for (int r = 0; r < 4; ++r){
        st[rt][0][r] += am[rt][0][r] + b0;
        st[rt][1][r] += am[rt][1][r] + b1;
      }
  };

  float xar[2][2][4];
#pragma unroll
  for (int rt = 0; rt < 2; ++rt)
#pragma unroll
    for (int r = 0; r < 4; ++r){
      int row = r0 + rt*16 + lq*4 + r; if (row >= N) row = N - 1;
      const int lrow = rt*16 + lq*4 + r;
      float v0 = ssp(x[(size_t)row*128 + col0]);
      float v1 = ssp(x[(size_t)row*128 + col1]);
      xar[rt][0][r] = v0; xar[rt][1][r] = v1;
      frag_put(0, lrow, q0c, e0c, v0);
      frag_put(0, lrow, q1c, e1c, v1);
    }
  __syncthreads();

  gemm(wcf + 0);
  float vst[2][2][4];
  {
    const float b0 = bi[col0], b1 = bi[col1];
#pragma unroll
    for (int rt = 0; rt < 2; ++rt)
#pragma unroll
      for (int r = 0; r < 4; ++r){
        int row = r0 + rt*16 + lq*4 + r; if (row >= N) row = N - 1;
        vst[rt][0][r] = vacc[(size_t)row*128 + col0] + ssp(am[rt][0][r] + b0);
        vst[rt][1][r] = vacc[(size_t)row*128 + col1] + ssp(am[rt][1][r] + b1);
      }
  }

  for (int kk = 0; kk < ni; ++kk)
    residual(vst, wcf + (size_t)(1 + kk) * 4096, bint + kk*128);

  put_ssp_state(vst);
  gemm(wcf + (size_t)(1 + ni) * 4096);
  float hst[2][2][4];
  {
    const float b0 = bf_[col0], b1 = bf_[col1];
    const float u0 = u[col0],   u1 = u[col1];
#pragma unroll
    for (int rt = 0; rt < 2; ++rt)
#pragma unroll
      for (int r = 0; r < 4; ++r){
        hst[rt][0][r] = u0 * xar[rt][0][r] + am[rt][0][r] + b0;
        hst[rt][1][r] = u1 * xar[rt][1][r] + am[rt][1][r] + b1;
      }
  }

  for (int kk = 0; kk < na; ++kk)
    residual(hst, wcf + (size_t)(2 + ni + kk) * 4096, batm + kk*128);

#pragma unroll
  for (int rt = 0; rt < 2; ++rt)
#pragma unroll
    for (int r = 0; r < 4; ++r){
      const int row = r0 + rt*16 + lq*4 + r;
      if (row < N){
        out[(size_t)N*128 + (size_t)row*128 + col0] = hst[rt][0][r];
        out[(size_t)N*128 + (size_t)row*128 + col1] = hst[rt][1][r];
      }
    }

  for (int kk = 0; kk < no; ++kk)
    residual(hst, wcf + (size_t)(2 + ni + na + kk) * 4096, bout + kk*128);

#pragma unroll
  for (int rt = 0; rt < 2; ++rt)
#pragma unroll
    for (int r = 0; r < 4; ++r){
      const int row = r0 + rt*16 + lq*4 + r;
      if (row < N){
        out[(size_t)row*128 + col0] = ssp(hst[rt][0][r]);
        out[(size_t)row*128 + col1] = ssp(hst[rt][1][r]);
      }
    }
}

// ---------- launch (6 dispatches) ----------
extern "C" void kernel_launch(void* const* d_in, const int* in_sizes, int n_in,
                              void* d_out, int out_size, void* d_ws, size_t ws_size,
                              hipStream_t stream)
{
  const float* x    = (const float*)d_in[0];
  const float* g    = (const float*)d_in[1];
  const float* Wf   = (const float*)d_in[2];
  const float* bf_  = (const float*)d_in[3];
  const float* Wg   = (const float*)d_in[4];
  const float* Wj   = (const float*)d_in[5];
  const float* bj   = (const float*)d_in[6];
  const float* Wi   = (const float*)d_in[7];
  const float* bi   = (const float*)d_in[8];
  const float* u    = (const float*)d_in[9];
  const float* Wint = (const float*)d_in[10];
  const float* bint = (const float*)d_in[11];
  const float* Watm = (const float*)d_in[12];
  const float* batm = (const float*)d_in[13];
  const float* Wout = (const float*)d_in[14];
  const float* bout = (const float*)d_in[15];
  const int* idx_i  = (const int*)d_in[16];
  const int* idx_j  = (const int*)d_in[17];

  const int N  = in_sizes[0] / 128;
  const int E  = in_sizes[16];
  const int ni = in_sizes[10] / 16384;
  const int na = in_sizes[12] / 16384;
  const int no = in_sizes[14] / 16384;

  const int nmat = 3 + ni + na + no;

  // vacc aliases the o-half of d_out (consumed before o is written).
  float* vacc = (float*)d_out;
  short8* wsf = (short8*)d_ws;
  const short8* wjf = wsf;                       // slot 0
  const short8* wcf = wsf + (size_t)1 * 4096;    // slots 1..nmat-1 (chain)
  const short8* wgf = wsf + (size_t)nmat * 4096; // slot nmat (Wg)

  // d_ws layout after frags: cnt[N] (doubles as ofs), bsums[1024], perm[E], xs
  const size_t frag_bytes = (size_t)(nmat + 1) * 65536;
  int* cnt   = (int*)((char*)d_ws + frag_bytes);
  int* bsums = cnt + N;
  int* perm  = bsums + 1024;
  char* after = (char*)(perm + E);
  const size_t used = (size_t)(after - (char*)d_ws);
  const size_t xs_bytes = (size_t)N * 256 * sizeof(unsigned short);
  unsigned short* xs = (ws_size >= used + xs_bytes)
      ? (unsigned short*)after
      : (unsigned short*)((float*)d_out + (size_t)N * 128);

  const int nblk = (N + 2047) / 2048;
  const int pref_fold = (nblk <= 64) ? 1 : 0;

  k_xconv  <<<dim3((N*128/4 + 255)/256), dim3(256), 0, stream>>>(x, xs, vacc, cnt, N * 128);
  k_wconv  <<<dim3((nmat + 1) * 8), dim3(256), 0, stream>>>(Wj, Wg, Wi, Wf, Wint, Watm, Wout,
                                                            (unsigned short*)d_ws, ni, na, no,
                                                            idx_i, cnt, E);
  k_scan1  <<<dim3(nblk), dim3(256), 0, stream>>>(cnt, bsums, N);
  if (!pref_fold)
    k_scan2<<<dim3(1), dim3(64), 0, stream>>>(bsums, nblk);
  k_scatter<<<dim3((E + 255)/256), dim3(256), 0, stream>>>(idx_i, cnt, bsums, perm, E,
                                                           nblk, pref_fold);
  k_edge   <<<dim3((E + 127)/128), dim3(256), 0, stream>>>(xs, g, idx_i, idx_j, perm,
                                                           wjf, wgf, bj, vacc, E);
  k_chain  <<<dim3((N + 31)/32), dim3(256), 0, stream>>>(x, vacc, wcf,
                                                         bi, bf_, u, bint, batm, bout,
                                                         (float*)d_out, N, ni, na, no);
}